// Round 4
// baseline (221.231 us; speedup 1.0000x reference)
//
#include <hip/hip_runtime.h>
#include <hip/hip_bf16.h>
#include <stdint.h>

#define M_DIM 2048
#define N_DIM 4096
#define K_DIM 4096
#define NGROUP 32
#define GSIZE 128

// GEMM tiling: 128x128 block, 4 waves (2x2), each wave 64x64 via 2x2 of
// 32x32x32 i8 MFMA. BK = 256 codes = 2 quant groups per stage.
#define BM 128
#define BN 128
#define BKB 256        // bytes per LDS row = 16 chunks of 16 B

typedef __attribute__((ext_vector_type(4)))  int   int32x4_t;
typedef __attribute__((ext_vector_type(16))) int   int32x16_t;
typedef __attribute__((ext_vector_type(16))) float f32x16_t;

// global -> LDS direct DMA, 16 B per lane. LDS dst is wave-uniform base +
// lane*16 (m104/m108); data placement chosen via per-lane global address.
static __device__ __forceinline__ void gl2lds16(const void* g, void* l) {
    auto gp = (const __attribute__((address_space(1))) unsigned int*)(uintptr_t)g;
    auto lp = (__attribute__((address_space(3))) unsigned int*)(uintptr_t)l;
    __builtin_amdgcn_global_load_lds(gp, lp, 16, 0, 0);
}

// ---------------------------------------------------------------------------
// Fused prep:
//   [0, 2048): per-token activation quant -> A8 = (q-128) int8, xscale, czp
//   [2048, ..): weight dequant -> Bt8 = (code-wzp) int8, plus
//        WS[n] += ws[n][g] * sum_g(code-wzp) via one atomic per 16-lane group
// ---------------------------------------------------------------------------
#define QUANT_BLOCKS M_DIM
#define DEQ_BLOCKS ((N_DIM * K_DIM) / 8 / 256)       // 8 codes / thread

__global__ __launch_bounds__(256) void prep_kernel(
        const float* __restrict__ x,
        const int* __restrict__ qw,          // [N][K] codes 0..15 as int32
        const float* __restrict__ wsc,       // [N][32]
        const int* __restrict__ wzp,         // [N][32]
        char* __restrict__ A8,               // [M][K] int8 (q-128)
        char* __restrict__ Bt8,              // [N][K] int8 (code-wzp)
        float* __restrict__ xscale,          // [M]
        float* __restrict__ xzpc,            // [M]  = 128 - zp
        float* __restrict__ WS)              // [N]  (pre-zeroed; atomics)
{
    const int t = threadIdx.x;
    if (blockIdx.x < QUANT_BLOCKS) {
        const int s = blockIdx.x;
        const float* xrow = x + (size_t)s * K_DIM;

        float xv[16];
        float vmin = 1e38f, vmax = -1e38f;
#pragma unroll
        for (int p = 0; p < 4; ++p) {
            float4 v = *((const float4*)(xrow + p * 1024) + t);
            xv[p*4+0] = v.x; xv[p*4+1] = v.y; xv[p*4+2] = v.z; xv[p*4+3] = v.w;
            vmin = fminf(vmin, fminf(fminf(v.x, v.y), fminf(v.z, v.w)));
            vmax = fmaxf(vmax, fmaxf(fmaxf(v.x, v.y), fmaxf(v.z, v.w)));
        }
#pragma unroll
        for (int off = 32; off > 0; off >>= 1) {
            vmin = fminf(vmin, __shfl_xor(vmin, off));
            vmax = fmaxf(vmax, __shfl_xor(vmax, off));
        }
        __shared__ float smin[4], smax[4];
        const int wave = t >> 6;
        if ((t & 63) == 0) { smin[wave] = vmin; smax[wave] = vmax; }
        __syncthreads();
        vmin = fminf(fminf(smin[0], smin[1]), fminf(smin[2], smin[3]));
        vmax = fmaxf(fmaxf(smax[0], smax[1]), fmaxf(smax[2], smax[3]));

        float sc = (vmax - vmin) / 255.0f;
        sc = fmaxf(sc, 1e-5f);
        float zp = rintf(-vmin / sc);
        zp = fminf(fmaxf(zp, 0.0f), 255.0f);

#pragma unroll
        for (int p = 0; p < 4; ++p) {
            int b[4];
#pragma unroll
            for (int e = 0; e < 4; ++e) {
                float q = fminf(fmaxf(rintf(xv[p*4+e] / sc) + zp, 0.0f), 255.0f);
                b[e] = (int)q - 128;
            }
            unsigned pack = (b[0] & 0xff) | ((b[1] & 0xff) << 8) |
                            ((b[2] & 0xff) << 16) | ((b[3] & 0xff) << 24);
            *(unsigned*)(A8 + (size_t)s * K_DIM + p * 1024 + t * 4) = pack;
        }
        if (t == 0) { xscale[s] = sc; xzpc[s] = 128.0f - zp; }
    } else {
        // ---- weight dequant: 8 codes/thread; 16-lane cluster = 1 group ----
        const size_t base = ((size_t)(blockIdx.x - QUANT_BLOCKS) * 256 + t) * 8;
        const int n = (int)(base >> 12);          // /4096
        const int g = (int)((base >> 7) & 31);
        const int zp = wzp[n * NGROUP + g];

        int4 c0 = *(const int4*)(qw + base);
        int4 c1 = *(const int4*)(qw + base + 4);
        int v0 = c0.x - zp, v1 = c0.y - zp, v2 = c0.z - zp, v3 = c0.w - zp;
        int v4 = c1.x - zp, v5 = c1.y - zp, v6 = c1.z - zp, v7 = c1.w - zp;
        uint2 pk;
        pk.x = (v0 & 0xff) | ((v1 & 0xff) << 8) | ((v2 & 0xff) << 16) | ((v3 & 0xff) << 24);
        pk.y = (v4 & 0xff) | ((v5 & 0xff) << 8) | ((v6 & 0xff) << 16) | ((v7 & 0xff) << 24);
        *(uint2*)(Bt8 + base) = pk;

        int s8 = v0 + v1 + v2 + v3 + v4 + v5 + v6 + v7;
#pragma unroll
        for (int off = 1; off < 16; off <<= 1) s8 += __shfl_xor(s8, off);
        if ((t & 15) == 0)
            atomicAdd(WS + n, wsc[n * NGROUP + g] * (float)s8);
    }
}

// ---------------------------------------------------------------------------
// i8 grouped GEMM, 32x32x32 MFMA. Per group g: iacc += A8 x Bt8 (exact i32),
// facc += Ssc[g][n] * (float)iacc. Epilogue:
//   out[m][n] = xscale[m] * (facc + czp[m]*WS[n]) + bias[n]
// LDS: row-major [rows][256 B], 16B chunk c of row r stored at slot c^(r&7)
// (same conflict-free family as R2/R3: every 8 consecutive lanes of a
// fragment read cover 8 distinct chunk columns). wscales slab for the
// block's 128 columns staged transposed in LDS once at start.
// ---------------------------------------------------------------------------
__global__ __launch_bounds__(256, 2) void gemm_kernel(
        const char* __restrict__ A8,     // [M][K] int8
        const char* __restrict__ Bt8,    // [N][K] int8
        const float* __restrict__ xscale,
        const float* __restrict__ xzpc,
        const float* __restrict__ wsc,   // [N][32]
        const float* __restrict__ WS,    // [N]
        const float* __restrict__ bias,  // [N]
        float* __restrict__ out)         // [M][N] f32
{
    __shared__ __align__(16) char As[BM * BKB];      // 32 KiB
    __shared__ __align__(16) char Bs[BN * BKB];      // 32 KiB
    __shared__ float Ssc[NGROUP * BN];               // 16 KiB, [g][n]

    const int tid  = threadIdx.x;
    const int bm   = blockIdx.y;
    const int bn   = blockIdx.x;
    const int wave = tid >> 6;
    const int lane = tid & 63;
    const int wr   = (wave >> 1) * 64;   // wave row offset in 128
    const int wc   = (wave & 1) * 64;    // wave col offset in 128
    const int l31  = lane & 31;
    const int hi   = lane >> 5;          // 0/1
    const int l7   = l31 & 7;            // (row&7) for swizzle decode

    // stage wscales slab transposed: Ssc[g][n] = wsc[n0+n][g]
    const int n0 = bn * BN;
    {
        const int n = tid >> 1, gh = (tid & 1) * 16;
        const float4* src = (const float4*)(wsc + (size_t)(n0 + n) * NGROUP + gh);
#pragma unroll
        for (int j4 = 0; j4 < 4; ++j4) {
            float4 v = src[j4];
            Ssc[(gh + j4 * 4 + 0) * BN + n] = v.x;
            Ssc[(gh + j4 * 4 + 1) * BN + n] = v.y;
            Ssc[(gh + j4 * 4 + 2) * BN + n] = v.z;
            Ssc[(gh + j4 * 4 + 3) * BN + n] = v.w;
        }
    }

    int32x16_t iacc[2][2];
    f32x16_t   facc[2][2];
    int32x16_t ZERO;
#pragma unroll
    for (int r = 0; r < 16; ++r) ZERO[r] = 0;
#pragma unroll
    for (int i = 0; i < 2; ++i)
#pragma unroll
        for (int j = 0; j < 2; ++j) {
            iacc[i][j] = ZERO;
#pragma unroll
            for (int r = 0; r < 16; ++r) facc[i][j][r] = 0.0f;
        }

    const char* Ab = A8  + (size_t)(bm * BM) * K_DIM;
    const char* Bb = Bt8 + (size_t)(bn * BN) * K_DIM;

    // staging: each gl2lds16 covers 4 rows x 16 chunks; 32 slabs each for
    // A and B; wave handles 8 of each.
    const int srow4 = lane >> 4;          // row within 4-row slab

    for (int kt = 0; kt < K_DIM / BKB; ++kt) {   // 16 stages
        const int k0 = kt * BKB;
        __syncthreads();
#pragma unroll
        for (int p = 0; p < 8; ++p) {
            const int rbase = (p * 4 + wave) * 4;          // wave-uniform
            const int r = rbase + srow4;
            const int cdat = (lane & 15) ^ (r & 7);
            gl2lds16(Ab + (size_t)r * K_DIM + k0 + cdat * 16, As + rbase * BKB);
            gl2lds16(Bb + (size_t)r * K_DIM + k0 + cdat * 16, Bs + rbase * BKB);
        }
        __syncthreads();

#pragma unroll
        for (int half = 0; half < 2; ++half) {   // one quant group each
            const int g = kt * 2 + half;
            // per-group scales for this wave's two 32-col tiles (LDS, 2-way max)
            float scl[2];
            scl[0] = Ssc[g * BN + wc + 0  + l31];
            scl[1] = Ssc[g * BN + wc + 32 + l31];

#pragma unroll
            for (int ks4 = 0; ks4 < 4; ++ks4) {
                const int ks = half * 4 + ks4;
                const int cc = ks * 2 + hi;          // wanted 16B chunk
                int32x4_t af[2], bf[2];
#pragma unroll
                for (int i = 0; i < 2; ++i)
                    af[i] = *(const int32x4_t*)(As + (wr + i * 32 + l31) * BKB + ((cc ^ l7) * 16));
#pragma unroll
                for (int j = 0; j < 2; ++j)
                    bf[j] = *(const int32x4_t*)(Bs + (wc + j * 32 + l31) * BKB + ((cc ^ l7) * 16));
#pragma unroll
                for (int i = 0; i < 2; ++i)
#pragma unroll
                    for (int j = 0; j < 2; ++j)
                        iacc[i][j] = __builtin_amdgcn_mfma_i32_32x32x32_i8(
                            af[i], bf[j], ks4 == 0 ? ZERO : iacc[i][j], 0, 0, 0);
            }

            // fold this group's integer acc with its weight scale
#pragma unroll
            for (int i = 0; i < 2; ++i)
#pragma unroll
                for (int j = 0; j < 2; ++j)
#pragma unroll
                    for (int r = 0; r < 16; ++r)
                        facc[i][j][r] += scl[j] * (float)iacc[i][j][r];
        }
    }

    // Epilogue: 32x32 C/D layout col=lane&31, row=(reg&3)+8*(reg>>2)+4*hi
    const int m0 = bm * BM + wr;
#pragma unroll
    for (int j = 0; j < 2; ++j) {
        const int n = n0 + wc + j * 32 + l31;
        const float wsn = WS[n];
        const float bb  = bias[n];
#pragma unroll
        for (int i = 0; i < 2; ++i) {
#pragma unroll
            for (int r = 0; r < 16; ++r) {
                const int m = m0 + i * 32 + (r & 3) + 8 * (r >> 2) + 4 * hi;
                const float xs  = xscale[m];
                const float czp = xzpc[m];
                out[(size_t)m * N_DIM + n] = xs * (facc[i][j][r] + czp * wsn) + bb;
            }
        }
    }
}

extern "C" void kernel_launch(void* const* d_in, const int* in_sizes, int n_in,
                              void* d_out, int out_size, void* d_ws, size_t ws_size,
                              hipStream_t stream) {
    const float* x     = (const float*)d_in[0];
    const int*   qw    = (const int*)d_in[1];
    const float* wsc   = (const float*)d_in[2];
    const int*   wzp   = (const int*)d_in[3];
    const float* bias  = (const float*)d_in[4];
    float* out = (float*)d_out;

    // workspace layout
    char* A8  = (char*)d_ws;                                   //  8 MiB
    char* Bt8 = A8 + (size_t)M_DIM * K_DIM;                    // 16 MiB
    float* xscale = (float*)(Bt8 + (size_t)N_DIM * K_DIM);     //  8 KiB
    float* xzpc   = xscale + M_DIM;                            //  8 KiB
    float* WS     = xzpc + M_DIM;                              // 16 KiB

    hipMemsetAsync(WS, 0, N_DIM * sizeof(float), stream);
    prep_kernel<<<QUANT_BLOCKS + DEQ_BLOCKS, 256, 0, stream>>>(
        x, qw, wsc, wzp, A8, Bt8, xscale, xzpc, WS);
    dim3 grid(N_DIM / BN, M_DIM / BM);
    gemm_kernel<<<grid, 256, 0, stream>>>(A8, Bt8, xscale, xzpc, wsc, WS, bias, out);
}